// Round 10
// baseline (250.920 us; speedup 1.0000x reference)
//
#include <hip/hip_runtime.h>

#define NN 50000
#define NE 800000
#define NPAD 50176
// dims: IN=256, HID=128, OUT=64
#define NSLICE 32
#define ESL 25000     // NE / NSLICE
#define HPN 25088     // hist nodes per part (2 parts)
#define HPW 12544     // packed words per part (49 KB LDS)
#define FPN 12544     // fill nodes per part (4 parts, 49 KB LDS)
#define GB 782        // gemm-1 blocks = ceil(NN/64)
#define NB 196        // node blocks = ceil(NN/256)

typedef __attribute__((ext_vector_type(8))) short bf16x8;
typedef __attribute__((ext_vector_type(4))) float f32x4;

__device__ __forceinline__ float u2f(unsigned u) { return __uint_as_float(u); }
__device__ __forceinline__ unsigned f2u(float f) { return __float_as_uint(f); }
__device__ __forceinline__ unsigned short f2bf(float f) {
    unsigned u = f2u(f);
    return (unsigned short)((u + (((u >> 16) & 1u) + 0x7fffu)) >> 16);  // RNE
}

// ---------------- W pre-transform (both weights, one launch) ----------------
// frag order: f = (((n>>4)*(K/8) + (k>>3))*16 + (n&15))*8 + (k&7)
__global__ __launch_bounds__(256) void wtrans_kernel(
    const float* __restrict__ W1, const float* __restrict__ W2,
    unsigned short* __restrict__ Wh1, unsigned short* __restrict__ Wl1,
    unsigned short* __restrict__ Wh2, unsigned short* __restrict__ Wl2,
    int* __restrict__ done_cnt) {
    if (blockIdx.x == 0 && threadIdx.x == 0) *done_cnt = 0;  // re-zero each replay
    int b = blockIdx.x;
    float w;
    unsigned short *ph, *pl;
    int f;
    if (b < 128) {  // W1: K=256, N=128
        int i = b * 256 + threadIdx.x;
        int k = i >> 7, n = i & 127;
        f = (((n >> 4) * 32 + (k >> 3)) * 16 + (n & 15)) * 8 + (k & 7);
        w = W1[i]; ph = Wh1; pl = Wl1;
    } else {        // W2: K=128, N=64
        int i = (b - 128) * 256 + threadIdx.x;
        int k = i >> 6, n = i & 63;
        f = (((n >> 4) * 16 + (k >> 3)) * 16 + (n & 15)) * 8 + (k & 7);
        w = W2[i]; ph = Wh2; pl = Wl2;
    }
    unsigned u = f2u(w);
    float lo = w - u2f(u & 0xffff0000u);
    ph[f] = (unsigned short)(u >> 16);
    pl[f] = (unsigned short)(f2u(lo) >> 16);
}

// ---------------- packed-ushort LDS histogram (no global atomics) ------------
__global__ __launch_bounds__(1024) void hist_kernel(
    const int* __restrict__ src, const int* __restrict__ dst,
    unsigned* __restrict__ cnt_sl) {
    __shared__ unsigned lcnt[HPW];
    const int b = blockIdx.x;
    const int side = b & 1;
    const int slice = (b >> 1) & (NSLICE - 1);
    const int part = b >> 6;
    const int* __restrict__ arr = side ? dst : src;
    const int base = part * HPN;
    for (int j = threadIdx.x; j < HPW; j += 1024) lcnt[j] = 0;
    __syncthreads();
    const int e0 = slice * ESL;
    for (int i = e0 + threadIdx.x; i < e0 + ESL; i += 1024) {
        int v = arr[i] - base;
        if ((unsigned)v < (unsigned)HPN)
            atomicAdd(&lcnt[v >> 1], 1u << ((v & 1) * 16));
    }
    __syncthreads();
    unsigned* o = cnt_sl + (size_t)b * HPW;
    for (int j = threadIdx.x; j < HPW; j += 1024) o[j] = lcnt[j];
}

// ------- norms + per-slice presum + block scan + inline scanB (last block) ---
__global__ __launch_bounds__(256) void norm_scanAB_kernel(
    const unsigned* __restrict__ cnt_sl, float* __restrict__ ns,
    float* __restrict__ nd, int* __restrict__ presum,
    int* __restrict__ pref, int* __restrict__ blk_sum,
    int* __restrict__ blk_ofs, int* __restrict__ done_cnt, int n) {
    __shared__ int lds[256];
    __shared__ int is_last;
    int i = blockIdx.x * 256 + threadIdx.x;
    int d_total = 0;
    if (i < n) {
        int part = (i >= HPN) ? 1 : 0;
        int w = (i - part * HPN) >> 1;
        int sh = (i & 1) * 16;
        int s_total = 0;
#pragma unroll
        for (int sl = 0; sl < NSLICE; sl++) {
            int bb = part * 64 + sl * 2;
            s_total += (cnt_sl[(size_t)bb * HPW + w] >> sh) & 0xffff;
            int c = (cnt_sl[(size_t)(bb + 1) * HPW + w] >> sh) & 0xffff;
            presum[sl * NPAD + i] = d_total;
            d_total += c;
        }
        ns[i] = rsqrtf(fmaxf((float)s_total, 1.0f));
        nd[i] = rsqrtf(fmaxf((float)d_total, 1.0f));
    }
    lds[threadIdx.x] = d_total;
    __syncthreads();
    for (int ofs = 1; ofs < 256; ofs <<= 1) {
        int t = (threadIdx.x >= ofs) ? lds[threadIdx.x - ofs] : 0;
        __syncthreads();
        lds[threadIdx.x] += t;
        __syncthreads();
    }
    if (i < n) pref[i] = lds[threadIdx.x] - d_total;
    if (threadIdx.x == 255) blk_sum[blockIdx.x] = lds[255];
    __threadfence();
    if (threadIdx.x == 0) {
        int c = atomicAdd(done_cnt, 1);
        is_last = (c == gridDim.x - 1);
    }
    __syncthreads();
    if (!is_last) return;
    __threadfence();  // acquire: make other blocks' blk_sum visible
    int v = (threadIdx.x < gridDim.x) ? blk_sum[threadIdx.x] : 0;
    __syncthreads();
    lds[threadIdx.x] = v;
    __syncthreads();
    for (int ofs = 1; ofs < 256; ofs <<= 1) {
        int t = (threadIdx.x >= ofs) ? lds[threadIdx.x - ofs] : 0;
        __syncthreads();
        lds[threadIdx.x] += t;
        __syncthreads();
    }
    if (threadIdx.x < gridDim.x) blk_ofs[threadIdx.x] = lds[threadIdx.x] - v;
}

// ---------------- atomic-free CSR fill (LDS cursors) ----------------
// row base computed as pref[gi] + blk_ofs[gi>>8] (scanC eliminated).
__global__ __launch_bounds__(1024) void fill_kernel(
    const int* __restrict__ src, const int* __restrict__ dst,
    const int* __restrict__ pref, const int* __restrict__ blk_ofs,
    const int* __restrict__ presum, int* __restrict__ eidx) {
    __shared__ int cur[FPN];
    const int slice = blockIdx.x >> 2;
    const int part = blockIdx.x & 3;
    const int base = part * FPN;
    for (int j = threadIdx.x; j < FPN; j += 1024) {
        int gi = base + j;
        cur[j] = (gi < NN) ? pref[gi] + blk_ofs[gi >> 8] + presum[slice * NPAD + gi] : 0;
    }
    __syncthreads();
    const int e0 = slice * ESL;
    for (int i = e0 + threadIdx.x; i < e0 + ESL; i += 1024) {
        int v = dst[i] - base;
        if ((unsigned)v < (unsigned)FPN) {
            int pos = atomicAdd(&cur[v], 1);
            eidx[pos] = src[i];
        }
    }
}

// ---------------- split-bf16 MFMA GEMM (fp32 A) — layer 1 ----------------
__global__ __launch_bounds__(256) void gemm1_kernel(
    const float* __restrict__ A, const unsigned short* __restrict__ Wh,
    const unsigned short* __restrict__ Wl, unsigned short* __restrict__ out, int M) {
    constexpr int N = 128, K = 256;
    constexpr int NT = N / 16, KC = K / 32;
    const int wave = threadIdx.x >> 6;
    const int lane = threadIdx.x & 63;
    const int ln = lane & 15;
    const int qk = lane >> 4;
    const int m0 = blockIdx.x * 64 + wave * 16;
    const int mA = m0 + ln;
    const float* Arow = A + (size_t)(mA < M ? mA : (M - 1)) * K + qk * 8;
    const bf16x8* BH = (const bf16x8*)Wh;
    const bf16x8* BL = (const bf16x8*)Wl;

    f32x4 acc[NT];
#pragma unroll
    for (int t = 0; t < NT; t++) acc[t] = (f32x4){0.f, 0.f, 0.f, 0.f};

#pragma unroll 2
    for (int c = 0; c < KC; ++c) {
        float4 a0 = *(const float4*)(Arow + c * 32);
        float4 a1 = *(const float4*)(Arow + c * 32 + 4);
        float av[8] = {a0.x, a0.y, a0.z, a0.w, a1.x, a1.y, a1.z, a1.w};
        bf16x8 ah, al;
#pragma unroll
        for (int j = 0; j < 8; ++j) {
            unsigned u = f2u(av[j]);
            float lo = av[j] - u2f(u & 0xffff0000u);
            ah[j] = (short)(u >> 16);
            al[j] = (short)(f2u(lo) >> 16);
        }
        const int fb = c * 4 + qk;
#pragma unroll
        for (int t = 0; t < NT; ++t) {
            bf16x8 bh = BH[(t * (K / 8) + fb) * 16 + ln];
            bf16x8 bl = BL[(t * (K / 8) + fb) * 16 + ln];
            acc[t] = __builtin_amdgcn_mfma_f32_16x16x32_bf16(ah, bh, acc[t], 0, 0, 0);
            acc[t] = __builtin_amdgcn_mfma_f32_16x16x32_bf16(ah, bl, acc[t], 0, 0, 0);
            acc[t] = __builtin_amdgcn_mfma_f32_16x16x32_bf16(al, bh, acc[t], 0, 0, 0);
        }
    }
#pragma unroll
    for (int t = 0; t < NT; ++t)
#pragma unroll
        for (int r = 0; r < 4; ++r) {
            int row = m0 + qk * 4 + r;
            if (row < M) out[(size_t)row * N + t * 16 + ln] = f2bf(acc[t][r]);
        }
}

// -------- fused layer 2: gather(hs1) -> LDS h1 tile -> bf16 MFMA GEMM --------
// Block = 256 thr, 16 dst nodes. Phase A: wave per node (4 each), lane owns
// 2 dims; h1 row (relu'd, bf16-packed) to LDS (stride 68 dw: 2-way banks).
// Phase B: wave t computes n-tile t of hs2[16 x 64] = h1 @ W2 (Ah exact bf16).
__global__ __launch_bounds__(256) void layer2_kernel(
    const unsigned* __restrict__ hs1, const int* __restrict__ eidx,
    const int* __restrict__ pref, const int* __restrict__ blk_ofs,
    const float* __restrict__ norm_src, const float* __restrict__ norm_dst,
    const float* __restrict__ bias, const unsigned short* __restrict__ Wh,
    const unsigned short* __restrict__ Wl, unsigned short* __restrict__ hs2, int n) {
    __shared__ unsigned lh1[16 * 68];
    const int wave = threadIdx.x >> 6;
    const int lane = threadIdx.x & 63;
    const int nb = blockIdx.x * 16;

    // Phase A: gather 4 nodes per wave
    for (int j = 0; j < 4; ++j) {
        const int node = nb + wave * 4 + j;
        float rx = 0.f, ry = 0.f;
        if (node < n) {
            int beg = pref[node] + blk_ofs[node >> 8];
            int end = (node + 1 < n) ? pref[node + 1] + blk_ofs[(node + 1) >> 8] : NE;
            float ax = 0.f, ay = 0.f;
            int e = beg;
            for (; e + 3 < end; e += 4) {
                int s0 = eidx[e], s1 = eidx[e + 1], s2 = eidx[e + 2], s3 = eidx[e + 3];
                float n0 = norm_src[s0], n1 = norm_src[s1];
                float n2 = norm_src[s2], n3 = norm_src[s3];
                unsigned u0 = hs1[(size_t)s0 * 64 + lane];
                unsigned u1 = hs1[(size_t)s1 * 64 + lane];
                unsigned u2 = hs1[(size_t)s2 * 64 + lane];
                unsigned u3 = hs1[(size_t)s3 * 64 + lane];
                ax += n0 * u2f(u0 << 16) + n1 * u2f(u1 << 16) +
                      n2 * u2f(u2 << 16) + n3 * u2f(u3 << 16);
                ay += n0 * u2f(u0 & 0xffff0000u) + n1 * u2f(u1 & 0xffff0000u) +
                      n2 * u2f(u2 & 0xffff0000u) + n3 * u2f(u3 & 0xffff0000u);
            }
            for (; e < end; ++e) {
                int s0 = eidx[e];
                float n0 = norm_src[s0];
                unsigned u0 = hs1[(size_t)s0 * 64 + lane];
                ax += n0 * u2f(u0 << 16);
                ay += n0 * u2f(u0 & 0xffff0000u);
            }
            float sc = norm_dst[node];
            float2 b = ((const float2*)bias)[lane];
            rx = fmaxf(ax * sc + b.x, 0.f);   // relu
            ry = fmaxf(ay * sc + b.y, 0.f);
        }
        lh1[(wave * 4 + j) * 68 + lane] = (unsigned)f2bf(rx) | ((unsigned)f2bf(ry) << 16);
    }
    __syncthreads();

    // Phase B: wave = n-tile t; K=128 (4 chunks), A from LDS, 2 MFMA terms
    const int ln = lane & 15;
    const int qk = lane >> 4;
    const int t = wave;
    const bf16x8* BH = (const bf16x8*)Wh;
    const bf16x8* BL = (const bf16x8*)Wl;
    f32x4 acc = (f32x4){0.f, 0.f, 0.f, 0.f};
#pragma unroll
    for (int c = 0; c < 4; ++c) {
        bf16x8 ah = *(const bf16x8*)&lh1[ln * 68 + c * 16 + qk * 4];
        const int fb = c * 4 + qk;
        bf16x8 bh = BH[(t * 16 + fb) * 16 + ln];
        bf16x8 bl = BL[(t * 16 + fb) * 16 + ln];
        acc = __builtin_amdgcn_mfma_f32_16x16x32_bf16(ah, bh, acc, 0, 0, 0);
        acc = __builtin_amdgcn_mfma_f32_16x16x32_bf16(ah, bl, acc, 0, 0, 0);
    }
#pragma unroll
    for (int r = 0; r < 4; ++r) {
        int node = nb + qk * 4 + r;
        if (node < n) hs2[(size_t)node * 64 + t * 16 + ln] = f2bf(acc[r]);
    }
}

// ---------------- final gather (D=64) + epilogue ----------------
__global__ __launch_bounds__(256) void gather64_kernel(
    const unsigned* __restrict__ hs, const int* __restrict__ eidx,
    const int* __restrict__ pref, const int* __restrict__ blk_ofs,
    const float* __restrict__ norm_src, const float* __restrict__ norm_dst,
    const float* __restrict__ bias, float* __restrict__ out, int n) {
    int wave = (blockIdx.x * blockDim.x + threadIdx.x) >> 6;
    int lane = threadIdx.x & 63;
    if (wave >= n) return;
    int beg = pref[wave] + blk_ofs[wave >> 8];
    int end = (wave + 1 < n) ? pref[wave + 1] + blk_ofs[(wave + 1) >> 8] : NE;
    int half = lane >> 5;
    int dim = lane & 31;
    float ax = 0.f, ay = 0.f;
    int e = beg + half;
    for (; e + 2 < end; e += 4) {
        int s0 = eidx[e], s1 = eidx[e + 2];
        float n0 = norm_src[s0], n1 = norm_src[s1];
        unsigned u0 = hs[(size_t)s0 * 32 + dim];
        unsigned u1 = hs[(size_t)s1 * 32 + dim];
        ax += n0 * u2f(u0 << 16) + n1 * u2f(u1 << 16);
        ay += n0 * u2f(u0 & 0xffff0000u) + n1 * u2f(u1 & 0xffff0000u);
    }
    if (e < end) {
        int s0 = eidx[e];
        float n0 = norm_src[s0];
        unsigned u0 = hs[(size_t)s0 * 32 + dim];
        ax += n0 * u2f(u0 << 16);
        ay += n0 * u2f(u0 & 0xffff0000u);
    }
    ax += __shfl_xor(ax, 32);
    ay += __shfl_xor(ay, 32);
    if (half == 0) {
        float sc = norm_dst[wave];
        float2 b = ((const float2*)bias)[dim];
        ((float2*)out)[(size_t)wave * 32 + dim] =
            make_float2(ax * sc + b.x, ay * sc + b.y);
    }
}

extern "C" void kernel_launch(void* const* d_in, const int* in_sizes, int n_in,
                              void* d_out, int out_size, void* d_ws, size_t ws_size,
                              hipStream_t stream) {
    const float* x  = (const float*)d_in[0];   // [50000,256]
    const float* W1 = (const float*)d_in[1];   // [256,128]
    const float* b1 = (const float*)d_in[2];   // [128]
    const float* W2 = (const float*)d_in[3];   // [128,64]
    const float* b2 = (const float*)d_in[4];   // [64]
    const int* src  = (const int*)d_in[5];     // [800000]
    const int* dst  = (const int*)d_in[6];     // [800000]
    float* out = (float*)d_out;                // [50000,64] fp32
    char* ws = (char*)d_ws;

    // ws layout (dword offsets)
    float* norm_src = (float*)(ws);                       // 50176
    float* norm_dst = (float*)(ws + 4 * 50176);           // 50176
    int*   pref     = (int*)(ws + 4 * 100352);            // 50176
    int*   blk_sum  = (int*)(ws + 4 * 150528);            // 256
    int*   blk_ofs  = (int*)(ws + 4 * 150784);            // 256
    int*   done_cnt = (int*)(ws + 4 * 151040);            // 256 (1 used)
    int*   eidx     = (int*)(ws + 4 * 151296);            // 800000
    unsigned short* Wh1 = (unsigned short*)(ws + 4 * 951296);   // 16384 dw
    unsigned short* Wl1 = (unsigned short*)(ws + 4 * 967680);   // 16384 dw
    unsigned short* Wh2 = (unsigned short*)(ws + 4 * 984064);   // 4096 dw
    unsigned short* Wl2 = (unsigned short*)(ws + 4 * 988160);   // 4096 dw
    unsigned short* hs1 = (unsigned short*)(ws + 4 * 992256);   // bf16 [50000,128]
    unsigned short* hs2 = (unsigned short*)(ws + 4 * 4192256);  // bf16 [50000,64]
    unsigned* cnt_sl    = (unsigned*)(ws + 4 * 5792256);        // 128*12544 dw
    int* presum         = (int*)(ws + 4 * 7397888);             // 32*50176 dw
    // end 9,003,520 dw ≈ 36 MB

    wtrans_kernel<<<160, 256, 0, stream>>>(W1, W2, Wh1, Wl1, Wh2, Wl2, done_cnt);

    hist_kernel<<<128, 1024, 0, stream>>>(src, dst, cnt_sl);
    gemm1_kernel<<<GB, 256, 0, stream>>>(x, Wh1, Wl1, hs1, NN);

    norm_scanAB_kernel<<<NB, 256, 0, stream>>>(cnt_sl, norm_src, norm_dst,
                                               presum, pref, blk_sum, blk_ofs,
                                               done_cnt, NN);
    fill_kernel<<<128, 1024, 0, stream>>>(src, dst, pref, blk_ofs, presum, eidx);

    layer2_kernel<<<3125, 256, 0, stream>>>(
        (const unsigned*)hs1, eidx, pref, blk_ofs, norm_src, norm_dst, b1,
        Wh2, Wl2, hs2, NN);

    gather64_kernel<<<12500, 256, 0, stream>>>(
        (const unsigned*)hs2, eidx, pref, blk_ofs, norm_src, norm_dst, b2, out, NN);
}

// Round 11
// 238.571 us; speedup vs baseline: 1.0518x; 1.0518x over previous
//
#include <hip/hip_runtime.h>

#define NN 50000
#define NE 800000
#define NPAD 50176
// dims: IN=256, HID=128, OUT=64
#define NSLICE 32
#define ESL 25000     // NE / NSLICE
#define HPN 25088     // hist nodes per part (2 parts)
#define HPW 12544     // packed words per part (49 KB LDS)
#define FPN 12544     // fill nodes per part (4 parts, 49 KB LDS)
#define GB 782        // gemm-1 blocks = ceil(NN/64)
#define NB 196        // node blocks = ceil(NN/256)

typedef __attribute__((ext_vector_type(8))) short bf16x8;
typedef __attribute__((ext_vector_type(4))) float f32x4;

__device__ __forceinline__ float u2f(unsigned u) { return __uint_as_float(u); }
__device__ __forceinline__ unsigned f2u(float f) { return __float_as_uint(f); }
__device__ __forceinline__ unsigned short f2bf(float f) {
    unsigned u = f2u(f);
    return (unsigned short)((u + (((u >> 16) & 1u) + 0x7fffu)) >> 16);  // RNE
}

// ------------- fused: packed-ushort LDS histogram + W pre-transform ----------
// Blocks [0,128): hist role — side(2) x slice(32) x part(2), LDS counters,
// no global atomics. Blocks [128,168): wtrans role — fragment-order W1/W2
// into bf16 hi/lo.  frag: f = (((n>>4)*(K/8) + (k>>3))*16 + (n&15))*8 + (k&7)
__global__ __launch_bounds__(1024) void hist_wtrans_kernel(
    const int* __restrict__ src, const int* __restrict__ dst,
    unsigned* __restrict__ cnt_sl,
    const float* __restrict__ W1, const float* __restrict__ W2,
    unsigned short* __restrict__ Wh1, unsigned short* __restrict__ Wl1,
    unsigned short* __restrict__ Wh2, unsigned short* __restrict__ Wl2,
    int* __restrict__ done_cnt) {
    if (blockIdx.x == 0 && threadIdx.x == 0) *done_cnt = 0;  // re-zero each replay
    const int b = blockIdx.x;
    if (b >= 128) {  // wtrans role
        float w;
        unsigned short *ph, *pl;
        int f;
        if (b < 160) {  // W1: K=256, N=128 (32768 elems, 32 blocks)
            int i = (b - 128) * 1024 + threadIdx.x;
            int k = i >> 7, n = i & 127;
            f = (((n >> 4) * 32 + (k >> 3)) * 16 + (n & 15)) * 8 + (k & 7);
            w = W1[i]; ph = Wh1; pl = Wl1;
        } else {        // W2: K=128, N=64 (8192 elems, 8 blocks)
            int i = (b - 160) * 1024 + threadIdx.x;
            int k = i >> 6, n = i & 63;
            f = (((n >> 4) * 16 + (k >> 3)) * 16 + (n & 15)) * 8 + (k & 7);
            w = W2[i]; ph = Wh2; pl = Wl2;
        }
        unsigned u = f2u(w);
        float lo = w - u2f(u & 0xffff0000u);
        ph[f] = (unsigned short)(u >> 16);
        pl[f] = (unsigned short)(f2u(lo) >> 16);
        return;
    }
    // hist role
    __shared__ unsigned lcnt[HPW];
    const int side = b & 1;
    const int slice = (b >> 1) & (NSLICE - 1);
    const int part = b >> 6;
    const int* __restrict__ arr = side ? dst : src;
    const int base = part * HPN;
    for (int j = threadIdx.x; j < HPW; j += 1024) lcnt[j] = 0;
    __syncthreads();
    const int e0 = slice * ESL;
    for (int i = e0 + threadIdx.x; i < e0 + ESL; i += 1024) {
        int v = arr[i] - base;
        if ((unsigned)v < (unsigned)HPN)
            atomicAdd(&lcnt[v >> 1], 1u << ((v & 1) * 16));
    }
    __syncthreads();
    unsigned* o = cnt_sl + (size_t)b * HPW;
    for (int j = threadIdx.x; j < HPW; j += 1024) o[j] = lcnt[j];
}

// ------- norms + per-slice presum + block scan + inline scanB (last block) ---
__global__ __launch_bounds__(256) void norm_scanAB_kernel(
    const unsigned* __restrict__ cnt_sl, float* __restrict__ ns,
    float* __restrict__ nd, int* __restrict__ presum,
    int* __restrict__ pref, int* __restrict__ blk_sum,
    int* __restrict__ blk_ofs, int* __restrict__ done_cnt, int n) {
    __shared__ int lds[256];
    __shared__ int is_last;
    int i = blockIdx.x * 256 + threadIdx.x;
    int d_total = 0;
    if (i < n) {
        int part = (i >= HPN) ? 1 : 0;
        int w = (i - part * HPN) >> 1;
        int sh = (i & 1) * 16;
        int s_total = 0;
#pragma unroll
        for (int sl = 0; sl < NSLICE; sl++) {
            int bb = part * 64 + sl * 2;
            s_total += (cnt_sl[(size_t)bb * HPW + w] >> sh) & 0xffff;
            int c = (cnt_sl[(size_t)(bb + 1) * HPW + w] >> sh) & 0xffff;
            presum[sl * NPAD + i] = d_total;
            d_total += c;
        }
        ns[i] = rsqrtf(fmaxf((float)s_total, 1.0f));
        nd[i] = rsqrtf(fmaxf((float)d_total, 1.0f));
    }
    lds[threadIdx.x] = d_total;
    __syncthreads();
    for (int ofs = 1; ofs < 256; ofs <<= 1) {
        int t = (threadIdx.x >= ofs) ? lds[threadIdx.x - ofs] : 0;
        __syncthreads();
        lds[threadIdx.x] += t;
        __syncthreads();
    }
    if (i < n) pref[i] = lds[threadIdx.x] - d_total;
    if (threadIdx.x == 255) blk_sum[blockIdx.x] = lds[255];
    __threadfence();
    if (threadIdx.x == 0) {
        int c = atomicAdd(done_cnt, 1);
        is_last = (c == gridDim.x - 1);
    }
    __syncthreads();
    if (!is_last) return;
    __threadfence();
    int v = (threadIdx.x < gridDim.x) ? blk_sum[threadIdx.x] : 0;
    __syncthreads();
    lds[threadIdx.x] = v;
    __syncthreads();
    for (int ofs = 1; ofs < 256; ofs <<= 1) {
        int t = (threadIdx.x >= ofs) ? lds[threadIdx.x - ofs] : 0;
        __syncthreads();
        lds[threadIdx.x] += t;
        __syncthreads();
    }
    if (threadIdx.x < gridDim.x) blk_ofs[threadIdx.x] = lds[threadIdx.x] - v;
}

// ---------------- atomic-free CSR fill (LDS cursors) ----------------
__global__ __launch_bounds__(1024) void fill_kernel(
    const int* __restrict__ src, const int* __restrict__ dst,
    const int* __restrict__ pref, const int* __restrict__ blk_ofs,
    const int* __restrict__ presum, int* __restrict__ eidx) {
    __shared__ int cur[FPN];
    const int slice = blockIdx.x >> 2;
    const int part = blockIdx.x & 3;
    const int base = part * FPN;
    for (int j = threadIdx.x; j < FPN; j += 1024) {
        int gi = base + j;
        cur[j] = (gi < NN) ? pref[gi] + blk_ofs[gi >> 8] + presum[slice * NPAD + gi] : 0;
    }
    __syncthreads();
    const int e0 = slice * ESL;
    for (int i = e0 + threadIdx.x; i < e0 + ESL; i += 1024) {
        int v = dst[i] - base;
        if ((unsigned)v < (unsigned)FPN) {
            int pos = atomicAdd(&cur[v], 1);
            eidx[pos] = src[i];
        }
    }
}

// ------- split-bf16 MFMA GEMM (fp32 A), row-scaled epilogue — layer 1 --------
// hs1[row] = (x @ W1)[row] * norm_src[row]  (bf16)
__global__ __launch_bounds__(256) void gemm1_kernel(
    const float* __restrict__ A, const unsigned short* __restrict__ Wh,
    const unsigned short* __restrict__ Wl, const float* __restrict__ norm_src,
    unsigned short* __restrict__ out, int M) {
    constexpr int N = 128, K = 256;
    constexpr int NT = N / 16, KC = K / 32;
    const int wave = threadIdx.x >> 6;
    const int lane = threadIdx.x & 63;
    const int ln = lane & 15;
    const int qk = lane >> 4;
    const int m0 = blockIdx.x * 64 + wave * 16;
    const int mA = m0 + ln;
    const float* Arow = A + (size_t)(mA < M ? mA : (M - 1)) * K + qk * 8;
    const bf16x8* BH = (const bf16x8*)Wh;
    const bf16x8* BL = (const bf16x8*)Wl;

    f32x4 acc[NT];
#pragma unroll
    for (int t = 0; t < NT; t++) acc[t] = (f32x4){0.f, 0.f, 0.f, 0.f};

#pragma unroll 2
    for (int c = 0; c < KC; ++c) {
        float4 a0 = *(const float4*)(Arow + c * 32);
        float4 a1 = *(const float4*)(Arow + c * 32 + 4);
        float av[8] = {a0.x, a0.y, a0.z, a0.w, a1.x, a1.y, a1.z, a1.w};
        bf16x8 ah, al;
#pragma unroll
        for (int j = 0; j < 8; ++j) {
            unsigned u = f2u(av[j]);
            float lo = av[j] - u2f(u & 0xffff0000u);
            ah[j] = (short)(u >> 16);
            al[j] = (short)(f2u(lo) >> 16);
        }
        const int fb = c * 4 + qk;
#pragma unroll
        for (int t = 0; t < NT; ++t) {
            bf16x8 bh = BH[(t * (K / 8) + fb) * 16 + ln];
            bf16x8 bl = BL[(t * (K / 8) + fb) * 16 + ln];
            acc[t] = __builtin_amdgcn_mfma_f32_16x16x32_bf16(ah, bh, acc[t], 0, 0, 0);
            acc[t] = __builtin_amdgcn_mfma_f32_16x16x32_bf16(ah, bl, acc[t], 0, 0, 0);
            acc[t] = __builtin_amdgcn_mfma_f32_16x16x32_bf16(al, bh, acc[t], 0, 0, 0);
        }
    }
    float sc[4];
#pragma unroll
    for (int r = 0; r < 4; ++r) {
        int row = m0 + qk * 4 + r;
        sc[r] = (row < M) ? norm_src[row] : 0.f;
    }
#pragma unroll
    for (int t = 0; t < NT; ++t)
#pragma unroll
        for (int r = 0; r < 4; ++r) {
            int row = m0 + qk * 4 + r;
            if (row < M) out[(size_t)row * N + t * 16 + ln] = f2bf(acc[t][r] * sc[r]);
        }
}

// -------- fused layer 2: gather(hs1) -> LDS h1 tile -> bf16 MFMA GEMM --------
// hs1 rows pre-scaled by norm_src => gather is a plain sum. Phase B epilogue
// scales hs2 rows by norm_src (consumed by gather64 as plain sum).
__global__ __launch_bounds__(256) void layer2_kernel(
    const unsigned* __restrict__ hs1, const int* __restrict__ eidx,
    const int* __restrict__ pref, const int* __restrict__ blk_ofs,
    const float* __restrict__ norm_src, const float* __restrict__ norm_dst,
    const float* __restrict__ bias, const unsigned short* __restrict__ Wh,
    const unsigned short* __restrict__ Wl, unsigned short* __restrict__ hs2, int n) {
    __shared__ unsigned lh1[16 * 68];
    const int wave = threadIdx.x >> 6;
    const int lane = threadIdx.x & 63;
    const int nb = blockIdx.x * 16;

    // Phase A: gather 4 nodes per wave, 8 edges in flight
    for (int j = 0; j < 4; ++j) {
        const int node = nb + wave * 4 + j;
        float rx = 0.f, ry = 0.f;
        if (node < n) {
            int beg = pref[node] + blk_ofs[node >> 8];
            int end = (node + 1 < n) ? pref[node + 1] + blk_ofs[(node + 1) >> 8] : NE;
            float ax = 0.f, ay = 0.f;
            int e = beg;
            for (; e + 7 < end; e += 8) {
                unsigned u0 = hs1[(size_t)eidx[e] * 64 + lane];
                unsigned u1 = hs1[(size_t)eidx[e + 1] * 64 + lane];
                unsigned u2 = hs1[(size_t)eidx[e + 2] * 64 + lane];
                unsigned u3 = hs1[(size_t)eidx[e + 3] * 64 + lane];
                unsigned u4 = hs1[(size_t)eidx[e + 4] * 64 + lane];
                unsigned u5 = hs1[(size_t)eidx[e + 5] * 64 + lane];
                unsigned u6 = hs1[(size_t)eidx[e + 6] * 64 + lane];
                unsigned u7 = hs1[(size_t)eidx[e + 7] * 64 + lane];
                ax += u2f(u0 << 16) + u2f(u1 << 16) + u2f(u2 << 16) + u2f(u3 << 16) +
                      u2f(u4 << 16) + u2f(u5 << 16) + u2f(u6 << 16) + u2f(u7 << 16);
                ay += u2f(u0 & 0xffff0000u) + u2f(u1 & 0xffff0000u) +
                      u2f(u2 & 0xffff0000u) + u2f(u3 & 0xffff0000u) +
                      u2f(u4 & 0xffff0000u) + u2f(u5 & 0xffff0000u) +
                      u2f(u6 & 0xffff0000u) + u2f(u7 & 0xffff0000u);
            }
            for (; e + 3 < end; e += 4) {
                unsigned u0 = hs1[(size_t)eidx[e] * 64 + lane];
                unsigned u1 = hs1[(size_t)eidx[e + 1] * 64 + lane];
                unsigned u2 = hs1[(size_t)eidx[e + 2] * 64 + lane];
                unsigned u3 = hs1[(size_t)eidx[e + 3] * 64 + lane];
                ax += u2f(u0 << 16) + u2f(u1 << 16) + u2f(u2 << 16) + u2f(u3 << 16);
                ay += u2f(u0 & 0xffff0000u) + u2f(u1 & 0xffff0000u) +
                      u2f(u2 & 0xffff0000u) + u2f(u3 & 0xffff0000u);
            }
            for (; e < end; ++e) {
                unsigned u0 = hs1[(size_t)eidx[e] * 64 + lane];
                ax += u2f(u0 << 16);
                ay += u2f(u0 & 0xffff0000u);
            }
            float sc = norm_dst[node];
            float2 b = ((const float2*)bias)[lane];
            rx = fmaxf(ax * sc + b.x, 0.f);   // relu
            ry = fmaxf(ay * sc + b.y, 0.f);
        }
        lh1[(wave * 4 + j) * 68 + lane] = (unsigned)f2bf(rx) | ((unsigned)f2bf(ry) << 16);
    }
    __syncthreads();

    // Phase B: wave = n-tile t; K=128, A from LDS, 2 MFMA terms; scale rows.
    const int ln = lane & 15;
    const int qk = lane >> 4;
    const int t = wave;
    const bf16x8* BH = (const bf16x8*)Wh;
    const bf16x8* BL = (const bf16x8*)Wl;
    f32x4 acc = (f32x4){0.f, 0.f, 0.f, 0.f};
#pragma unroll
    for (int c = 0; c < 4; ++c) {
        bf16x8 ah = *(const bf16x8*)&lh1[ln * 68 + c * 16 + qk * 4];
        const int fb = c * 4 + qk;
        bf16x8 bh = BH[(t * 16 + fb) * 16 + ln];
        bf16x8 bl = BL[(t * 16 + fb) * 16 + ln];
        acc = __builtin_amdgcn_mfma_f32_16x16x32_bf16(ah, bh, acc, 0, 0, 0);
        acc = __builtin_amdgcn_mfma_f32_16x16x32_bf16(ah, bl, acc, 0, 0, 0);
    }
#pragma unroll
    for (int r = 0; r < 4; ++r) {
        int node = nb + qk * 4 + r;
        if (node < n)
            hs2[(size_t)node * 64 + t * 16 + ln] = f2bf(acc[r] * norm_src[node]);
    }
}

// ---------------- final gather (D=64, plain sum) + epilogue ----------------
__global__ __launch_bounds__(256) void gather64_kernel(
    const unsigned* __restrict__ hs, const int* __restrict__ eidx,
    const int* __restrict__ pref, const int* __restrict__ blk_ofs,
    const float* __restrict__ norm_dst, const float* __restrict__ bias,
    float* __restrict__ out, int n) {
    int wave = (blockIdx.x * blockDim.x + threadIdx.x) >> 6;
    int lane = threadIdx.x & 63;
    if (wave >= n) return;
    int beg = pref[wave] + blk_ofs[wave >> 8];
    int end = (wave + 1 < n) ? pref[wave + 1] + blk_ofs[(wave + 1) >> 8] : NE;
    int half = lane >> 5;
    int dim = lane & 31;
    float ax = 0.f, ay = 0.f;
    int e = beg + half;
    for (; e + 6 < end; e += 8) {  // this half: e, e+2, e+4, e+6
        unsigned u0 = hs[(size_t)eidx[e] * 32 + dim];
        unsigned u1 = hs[(size_t)eidx[e + 2] * 32 + dim];
        unsigned u2 = hs[(size_t)eidx[e + 4] * 32 + dim];
        unsigned u3 = hs[(size_t)eidx[e + 6] * 32 + dim];
        ax += u2f(u0 << 16) + u2f(u1 << 16) + u2f(u2 << 16) + u2f(u3 << 16);
        ay += u2f(u0 & 0xffff0000u) + u2f(u1 & 0xffff0000u) +
              u2f(u2 & 0xffff0000u) + u2f(u3 & 0xffff0000u);
    }
    for (; e < end; e += 2) {
        unsigned u0 = hs[(size_t)eidx[e] * 32 + dim];
        ax += u2f(u0 << 16);
        ay += u2f(u0 & 0xffff0000u);
    }
    ax += __shfl_xor(ax, 32);
    ay += __shfl_xor(ay, 32);
    if (half == 0) {
        float sc = norm_dst[wave];
        float2 b = ((const float2*)bias)[dim];
        ((float2*)out)[(size_t)wave * 32 + dim] =
            make_float2(ax * sc + b.x, ay * sc + b.y);
    }
}

extern "C" void kernel_launch(void* const* d_in, const int* in_sizes, int n_in,
                              void* d_out, int out_size, void* d_ws, size_t ws_size,
                              hipStream_t stream) {
    const float* x  = (const float*)d_in[0];   // [50000,256]
    const float* W1 = (const float*)d_in[1];   // [256,128]
    const float* b1 = (const float*)d_in[2];   // [128]
    const float* W2 = (const float*)d_in[3];   // [128,64]
    const float* b2 = (const float*)d_in[4];   // [64]
    const int* src  = (const int*)d_in[5];     // [800000]
    const int* dst  = (const int*)d_in[6];     // [800000]
    float* out = (float*)d_out;                // [50000,64] fp32
    char* ws = (char*)d_ws;

    // ws layout (dword offsets)
    float* norm_src = (float*)(ws);                       // 50176
    float* norm_dst = (float*)(ws + 4 * 50176);           // 50176
    int*   pref     = (int*)(ws + 4 * 100352);            // 50176
    int*   blk_sum  = (int*)(ws + 4 * 150528);            // 256
    int*   blk_ofs  = (int*)(ws + 4 * 150784);            // 256
    int*   done_cnt = (int*)(ws + 4 * 151040);            // 256 (1 used)
    int*   eidx     = (int*)(ws + 4 * 151296);            // 800000
    unsigned short* Wh1 = (unsigned short*)(ws + 4 * 951296);   // 16384 dw
    unsigned short* Wl1 = (unsigned short*)(ws + 4 * 967680);   // 16384 dw
    unsigned short* Wh2 = (unsigned short*)(ws + 4 * 984064);   // 4096 dw
    unsigned short* Wl2 = (unsigned short*)(ws + 4 * 988160);   // 4096 dw
    unsigned short* hs1 = (unsigned short*)(ws + 4 * 992256);   // bf16 [50000,128]
    unsigned short* hs2 = (unsigned short*)(ws + 4 * 4192256);  // bf16 [50000,64]
    unsigned* cnt_sl    = (unsigned*)(ws + 4 * 5792256);        // 128*12544 dw
    int* presum         = (int*)(ws + 4 * 7397888);             // 32*50176 dw
    // end 9,003,520 dw ≈ 36 MB

    hist_wtrans_kernel<<<168, 1024, 0, stream>>>(src, dst, cnt_sl, W1, W2,
                                                 Wh1, Wl1, Wh2, Wl2, done_cnt);

    norm_scanAB_kernel<<<NB, 256, 0, stream>>>(cnt_sl, norm_src, norm_dst,
                                               presum, pref, blk_sum, blk_ofs,
                                               done_cnt, NN);

    gemm1_kernel<<<GB, 256, 0, stream>>>(x, Wh1, Wl1, norm_src, hs1, NN);

    fill_kernel<<<128, 1024, 0, stream>>>(src, dst, pref, blk_ofs, presum, eidx);

    layer2_kernel<<<3125, 256, 0, stream>>>(
        (const unsigned*)hs1, eidx, pref, blk_ofs, norm_src, norm_dst, b1,
        Wh2, Wl2, hs2, NN);

    gather64_kernel<<<12500, 256, 0, stream>>>(
        (const unsigned*)hs2, eidx, pref, blk_ofs, norm_dst, b2, out, NN);
}